// Round 1
// baseline (89.798 us; speedup 1.0000x reference)
//
#include <hip/hip_runtime.h>

// LocalCorrRatio: 4 correlation-ratio passes over (1,1,90,90,90) fp32 volumes.
// 90 % 9 == 0 -> no padding. Each pass: 1000 patches (10x10x10) of 9^3=729
// voxels, 32 Parzen-window bins. Final scalar:
//   out = -(1/12000) * sum over 4 configs, 1000 patches of eta^2.
// Config c: X = (c&1 ? y_pred : y_true), Y = the other; shift = (c>=2 ? 4 : 0)
// (jnp.roll by -4 means read index (i+4) % 90).

constexpr int   NPATCH = 1000;
constexpr int   WIN3   = 729;
constexpr float PRETERM = 961.0f;      // 1/sigma^2, sigma = 1/31

__global__ __launch_bounds__(256)
void cr_patch_kernel(const float* __restrict__ yt,
                     const float* __restrict__ yp,
                     float* __restrict__ etas)
{
    __shared__ float sx[WIN3];
    __shared__ float sy[WIN3];
    __shared__ float red[8];        // per-wave {sumx, sumx2}
    __shared__ float swA [4][32];   // per-wave per-bin sum(w)
    __shared__ float swxA[4][32];   // per-wave per-bin sum(w*x)

    const int bid  = blockIdx.x;
    const int conf = bid / NPATCH;
    const int p    = bid - conf * NPATCH;
    const int ph   = p / 100;
    const int pw   = (p / 10) % 10;
    const int pd   = p % 10;

    const float* X = (conf & 1) ? yp : yt;
    const float* Y = (conf & 1) ? yt : yp;
    const int shift = (conf >= 2) ? 4 : 0;

    const int tid  = threadIdx.x;
    const int wid  = tid >> 6;
    const int lane = tid & 63;

    // ---- Phase 1: global -> LDS stage + sum(x), sum(x^2) ----
    float sumx = 0.f, sumx2 = 0.f;
    for (int j = tid; j < WIN3; j += 256) {
        int dh  = j / 81;
        int rem = j - dh * 81;
        int dw  = rem / 9;
        int dd  = rem - dw * 9;
        int H = ph * 9 + dh + shift; if (H >= 90) H -= 90;
        int W = pw * 9 + dw + shift; if (W >= 90) W -= 90;
        int D = pd * 9 + dd + shift; if (D >= 90) D -= 90;
        int idx = (H * 90 + W) * 90 + D;
        float xv = X[idx];
        float yv = Y[idx];
        sx[j] = xv;
        sy[j] = yv;
        sumx  += xv;
        sumx2  = fmaf(xv, xv, sumx2);
    }
    #pragma unroll
    for (int m = 1; m < 64; m <<= 1) {
        sumx  += __shfl_xor(sumx,  m);
        sumx2 += __shfl_xor(sumx2, m);
    }
    if (lane == 0) { red[wid * 2] = sumx; red[wid * 2 + 1] = sumx2; }
    __syncthreads();

    const float tot_x  = red[0] + red[2] + red[4] + red[6];
    const float tot_x2 = red[1] + red[3] + red[5] + red[7];
    const float mean   = tot_x * (1.0f / 729.0f);

    // ---- Phase 2: bin-per-lane Parzen accumulation ----
    // lane -> bin = lane&31, voxel-group = wid*2 + (lane>>5)  (8 groups)
    const int   bin = lane & 31;
    const int   grp = wid * 2 + (lane >> 5);
    const float c   = (float)bin * (1.0f / 31.0f);

    float sw = 0.f, swx = 0.f;
    for (int j = grp; j < WIN3; j += 8) {
        float yv = sy[j];               // broadcast within 32-lane group
        float xv = sx[j];
        float d  = yv - c;
        float w  = __expf(-PRETERM * d * d);
        sw += w;
        swx = fmaf(w, xv, swx);
    }
    // combine the wave's two voxel-groups (lane ^ 32 has same bin)
    sw  += __shfl_xor(sw,  32);
    swx += __shfl_xor(swx, 32);
    if (lane < 32) { swA[wid][bin] = sw; swxA[wid][bin] = swx; }
    __syncthreads();

    // ---- Phase 3: finalize eta^2 (lanes 0..31 of wave 0) ----
    if (tid < 32) {
        float Sw  = swA [0][tid] + swA [1][tid] + swA [2][tid] + swA [3][tid];
        float Swx = swxA[0][tid] + swxA[1][tid] + swxA[2][tid] + swxA[3][tid];
        float mi  = Swx / (Sw + 1e-5f);     // mean_intensities (weights_norm denom)
        float dmu = mi - mean;
        float t   = Sw * dmu * dmu;
        float ts  = Sw;
        #pragma unroll
        for (int m = 1; m < 32; m <<= 1) {   // stays within lanes 0..31
            t  += __shfl_xor(t,  m);
            ts += __shfl_xor(ts, m);
        }
        if (tid == 0) {
            float bgv = t / ts;                                    // no eps (matches ref)
            float tv  = (tot_x2 - tot_x * tot_x * (1.0f / 729.0f)) * (1.0f / 728.0f);
            etas[bid] = bgv / (tv + 1e-5f);
        }
    }
}

__global__ __launch_bounds__(256)
void cr_reduce_kernel(const float* __restrict__ etas, float* __restrict__ out)
{
    __shared__ float red[4];
    float s = 0.f;
    for (int i = threadIdx.x; i < 4 * NPATCH; i += 256) s += etas[i];
    #pragma unroll
    for (int m = 1; m < 64; m <<= 1) s += __shfl_xor(s, m);
    if ((threadIdx.x & 63) == 0) red[threadIdx.x >> 6] = s;
    __syncthreads();
    if (threadIdx.x == 0)
        out[0] = -(red[0] + red[1] + red[2] + red[3]) * (1.0f / 12000.0f);
}

extern "C" void kernel_launch(void* const* d_in, const int* in_sizes, int n_in,
                              void* d_out, int out_size, void* d_ws, size_t ws_size,
                              hipStream_t stream)
{
    const float* y_true = (const float*)d_in[0];
    const float* y_pred = (const float*)d_in[1];
    float* out  = (float*)d_out;
    float* etas = (float*)d_ws;     // 4000 floats = 16 KB scratch

    cr_patch_kernel<<<4 * NPATCH, 256, 0, stream>>>(y_true, y_pred, etas);
    cr_reduce_kernel<<<1, 256, 0, stream>>>(etas, out);
}

// Round 2
// 89.524 us; speedup vs baseline: 1.0031x; 1.0031x over previous
//
#include <hip/hip_runtime.h>

// LocalCorrRatio: 4 correlation-ratio passes over (1,1,90,90,90) fp32 volumes.
// 90 % 9 == 0 -> no padding. Each pass: 1000 patches (9x9x9), 32 Parzen bins.
// out = -(1/12000) * sum over 4 configs x 1000 patches of eta^2.
// Config c: X = (c&1 ? y_pred : y_true), Y = other; shift = (c>=2 ? 4 : 0).
//
// R2 design: one wave per (config,patch). Voxels live in registers (12/lane),
// bins iterated in per-lane-rotated order with on-the-fly __shfl routing, so
// the inner loop has ZERO LDS traffic (R1 was LDS-issue-bound at ~5.8K
// ds_read_b32/CU/round). Expected compute floor: ~93M exps -> ~5us trans,
// ~16K VALU cyc/CU -> ~7us.

constexpr int   NPATCH  = 1000;
constexpr float PRETERM = 961.0f;   // 1/sigma^2, sigma = 1/31

__global__ __launch_bounds__(64)
void cr_patch_kernel(const float* __restrict__ yt,
                     const float* __restrict__ yp,
                     float* __restrict__ etas)
{
    const int bid  = blockIdx.x;
    const int conf = bid / NPATCH;
    const int p    = bid - conf * NPATCH;
    const int ph   = p / 100;
    const int pw   = (p / 10) % 10;
    const int pd   = p % 10;

    const float* __restrict__ X = (conf & 1) ? yp : yt;
    const float* __restrict__ Y = (conf & 1) ? yt : yp;
    const int shift = (conf >= 2) ? 4 : 0;

    const int lane = threadIdx.x;          // 0..63 (one wave per block)

    // ---- Load 729 voxels into registers: lane handles j = lane + 64*v ----
    float xs[12], ys[12];
    float sumx = 0.f, sumx2 = 0.f;

    auto load_voxel = [&](int j, float& xv, float& yv) {
        int dh  = j / 81;
        int rem = j - dh * 81;
        int dw  = rem / 9;
        int dd  = rem - dw * 9;
        int H = ph * 9 + dh + shift; if (H >= 90) H -= 90;
        int W = pw * 9 + dw + shift; if (W >= 90) W -= 90;
        int D = pd * 9 + dd + shift; if (D >= 90) D -= 90;
        int idx = (H * 90 + W) * 90 + D;
        xv = X[idx];
        yv = Y[idx];
    };

    #pragma unroll
    for (int v = 0; v < 11; ++v) {
        load_voxel(lane + (v << 6), xs[v], ys[v]);
        sumx  += xs[v];
        sumx2  = fmaf(xs[v], xs[v], sumx2);
    }
    if (lane < 729 - 11 * 64) {            // lanes 0..24 own a 12th voxel
        load_voxel(lane + 704, xs[11], ys[11]);
        sumx  += xs[11];
        sumx2  = fmaf(xs[11], xs[11], sumx2);
    } else {
        xs[11] = 0.f;                      // no effect on sums
        ys[11] = 10.f;                     // exp(-961*(10-c)^2) underflows to 0
    }

    #pragma unroll
    for (int m = 1; m < 64; m <<= 1) {
        sumx  += __shfl_xor(sumx,  m);
        sumx2 += __shfl_xor(sumx2, m);
    }
    const float mean = sumx * (1.0f / 729.0f);

    // ---- Parzen accumulation, rotated bin order + shfl routing ----
    // At step k, lane l computes bin (l&31 + k)&31 over its own voxels; the
    // lane owning bin (l&31) fetches that partial from lane ((l-k)&31 | hi).
    const int l5 = lane & 31;
    const int hi = lane & 32;
    float r_sw = 0.f, r_swx = 0.f;

    for (int k = 0; k < 32; ++k) {
        const int   b = (l5 + k) & 31;
        const float c = (float)b * (1.0f / 31.0f);
        float sw = 0.f, swx = 0.f;
        #pragma unroll
        for (int v = 0; v < 12; ++v) {
            float d = ys[v] - c;
            float w = __expf(-PRETERM * d * d);
            sw += w;
            swx = fmaf(w, xs[v], swx);
        }
        const int src = hi | ((l5 - k) & 31);
        r_sw  += __shfl(sw,  src, 64);
        r_swx += __shfl(swx, src, 64);
    }
    // combine the two half-wave voxel partitions (same bin at lane^32)
    r_sw  += __shfl_xor(r_sw,  32);
    r_swx += __shfl_xor(r_swx, 32);

    // ---- Finalize eta^2 ----
    float mi  = r_swx / (r_sw + 1e-5f);    // mean intensity per bin
    float dmu = mi - mean;
    float tn  = r_sw * dmu * dmu;          // bin_counts * (mi - mean)^2
    float td  = r_sw;                      // bin_counts
    #pragma unroll
    for (int m = 1; m < 32; m <<= 1) {     // reduce over 32 bins (halves mirror)
        tn += __shfl_xor(tn, m);
        td += __shfl_xor(td, m);
    }
    if (lane == 0) {
        float bgv = tn / td;
        float tv  = (sumx2 - sumx * sumx * (1.0f / 729.0f)) * (1.0f / 728.0f);
        etas[bid] = bgv / (tv + 1e-5f);
    }
}

__global__ __launch_bounds__(256)
void cr_reduce_kernel(const float* __restrict__ etas, float* __restrict__ out)
{
    __shared__ float red[4];
    float s = 0.f;
    for (int i = threadIdx.x; i < 4 * NPATCH; i += 256) s += etas[i];
    #pragma unroll
    for (int m = 1; m < 64; m <<= 1) s += __shfl_xor(s, m);
    if ((threadIdx.x & 63) == 0) red[threadIdx.x >> 6] = s;
    __syncthreads();
    if (threadIdx.x == 0)
        out[0] = -(red[0] + red[1] + red[2] + red[3]) * (1.0f / 12000.0f);
}

extern "C" void kernel_launch(void* const* d_in, const int* in_sizes, int n_in,
                              void* d_out, int out_size, void* d_ws, size_t ws_size,
                              hipStream_t stream)
{
    const float* y_true = (const float*)d_in[0];
    const float* y_pred = (const float*)d_in[1];
    float* out  = (float*)d_out;
    float* etas = (float*)d_ws;            // 4000 floats = 16 KB scratch

    cr_patch_kernel<<<4 * NPATCH, 64, 0, stream>>>(y_true, y_pred, etas);
    cr_reduce_kernel<<<1, 256, 0, stream>>>(etas, out);
}